// Round 18
// baseline (2351.567 us; speedup 1.0000x reference)
//
#include <hip/hip_runtime.h>

// ConvLSTM2D x2 — persistent cooperative version of the 230us R17 kernel.
// One 256-block x 1024-thr coop kernel runs phases j=0..8 internally
// (phase = R17's launch body: L1 t=2j,2j+1; L2 t=2j-2,2j-1), separated by 8
// grid barriers (phase-indexed counter + gen word, R5's proven recipe).
// Register discipline from R15/R17 (no weight arrays, one unified accU) —
// prior persistent attempts (R3/R5) were invalidated by accumulator/weight
// scratch spill, not barrier cost; this isolates the barrier cost cleanly.

typedef __bf16 bf16x8 __attribute__((ext_vector_type(8)));
typedef float f32x4 __attribute__((ext_vector_type(4)));

#define WPK_ELEMS 73728   // per layer: 18 kchunks * 8 ntiles * 64 lanes * 8
#define PLANE 524288      // 4*64*64*32 elems per plane

__device__ __forceinline__ float fsigmoid(float z) {
    return 1.0f / (1.0f + __expf(-z));
}
__device__ __forceinline__ float ftanh(float z) {
    z = fminf(15.0f, fmaxf(-15.0f, z));
    float e = __expf(2.0f * z);
    return (e - 1.0f) / (e + 1.0f);
}

__global__ __launch_bounds__(256) void pack_weights(
    const float* __restrict__ wk1, const float* __restrict__ wr1,
    const float* __restrict__ wk2, const float* __restrict__ wr2,
    __bf16* __restrict__ wpk)
{
    int i = blockIdx.x * 256 + threadIdx.x;
    if (i >= 2 * WPK_ELEMS) return;
    int layer = i / WPK_ELEMS;
    int r = i - layer * WPK_ELEMS;
    int j2 = r & 7;
    int L  = (r >> 3) & 63;
    int nt = (r >> 9) & 7;
    int cix = r >> 12;            // tap*2 + src
    int tap = cix >> 1, src = cix & 1;
    int s = ((L >> 4) << 3) + j2;
    int gate = nt & 3;
    int f = ((nt >> 2) << 4) + (L & 15);
    int n = (gate << 5) + f;
    const float* w = layer ? (src ? wr2 : wk2) : (src ? wr1 : wk1);
    wpk[i] = (__bf16)w[(tap * 32 + s) * 128 + n];
}

__device__ __forceinline__ bf16x8 cvt8(const float* p) {
    const float4 f0 = *(const float4*)p;
    const float4 f1 = *(const float4*)(p + 4);
    bf16x8 v;
    v[0] = (__bf16)f0.x; v[1] = (__bf16)f0.y;
    v[2] = (__bf16)f0.z; v[3] = (__bf16)f0.w;
    v[4] = (__bf16)f1.x; v[5] = (__bf16)f1.y;
    v[6] = (__bf16)f1.z; v[7] = (__bf16)f1.w;
    return v;
}

#define MFMA16(A0, A1, A2, A3, WP, ACC)                                                   \
    {                                                                                     \
        const bf16x8 w0 = WP[0], w1 = WP[64], w2 = WP[128], w3 = WP[192];                 \
        ACC[0][0] = __builtin_amdgcn_mfma_f32_16x16x32_bf16(A0, w0, ACC[0][0], 0, 0, 0);  \
        ACC[0][1] = __builtin_amdgcn_mfma_f32_16x16x32_bf16(A0, w1, ACC[0][1], 0, 0, 0);  \
        ACC[0][2] = __builtin_amdgcn_mfma_f32_16x16x32_bf16(A0, w2, ACC[0][2], 0, 0, 0);  \
        ACC[0][3] = __builtin_amdgcn_mfma_f32_16x16x32_bf16(A0, w3, ACC[0][3], 0, 0, 0);  \
        ACC[1][0] = __builtin_amdgcn_mfma_f32_16x16x32_bf16(A1, w0, ACC[1][0], 0, 0, 0);  \
        ACC[1][1] = __builtin_amdgcn_mfma_f32_16x16x32_bf16(A1, w1, ACC[1][1], 0, 0, 0);  \
        ACC[1][2] = __builtin_amdgcn_mfma_f32_16x16x32_bf16(A1, w2, ACC[1][2], 0, 0, 0);  \
        ACC[1][3] = __builtin_amdgcn_mfma_f32_16x16x32_bf16(A1, w3, ACC[1][3], 0, 0, 0);  \
        ACC[2][0] = __builtin_amdgcn_mfma_f32_16x16x32_bf16(A2, w0, ACC[2][0], 0, 0, 0);  \
        ACC[2][1] = __builtin_amdgcn_mfma_f32_16x16x32_bf16(A2, w1, ACC[2][1], 0, 0, 0);  \
        ACC[2][2] = __builtin_amdgcn_mfma_f32_16x16x32_bf16(A2, w2, ACC[2][2], 0, 0, 0);  \
        ACC[2][3] = __builtin_amdgcn_mfma_f32_16x16x32_bf16(A2, w3, ACC[2][3], 0, 0, 0);  \
        ACC[3][0] = __builtin_amdgcn_mfma_f32_16x16x32_bf16(A3, w0, ACC[3][0], 0, 0, 0);  \
        ACC[3][1] = __builtin_amdgcn_mfma_f32_16x16x32_bf16(A3, w1, ACC[3][1], 0, 0, 0);  \
        ACC[3][2] = __builtin_amdgcn_mfma_f32_16x16x32_bf16(A3, w2, ACC[3][2], 0, 0, 0);  \
        ACC[3][3] = __builtin_amdgcn_mfma_f32_16x16x32_bf16(A3, w3, ACC[3][3], 0, 0, 0);  \
    }

__global__ __launch_bounds__(1024, 1) void clstm_coop18(
    const float* __restrict__ x,
    const __bf16* __restrict__ wpk1, const __bf16* __restrict__ wpk2,
    const float* __restrict__ bias1, const float* __restrict__ bias2,
    __bf16* __restrict__ h1buf,       // 4 planes, t%4
    __bf16* __restrict__ h2buf,       // 2 parity planes (odd t)
    float* __restrict__ c1,           // 2 parity planes (odd t)
    float* __restrict__ c2,
    int* __restrict__ cnt,            // 9 phase counters
    int* __restrict__ gen,            // generation word
    float* __restrict__ out)
{
    __shared__ __bf16 tXA[6 * 66 * 36];
    __shared__ __bf16 tRA[6 * 66 * 36];
    __shared__ __bf16 tXB[4 * 66 * 36];
    __shared__ __bf16 tHA[4 * 66 * 36];
    __shared__ float  cpass[2 * 64 * 32];

    const int blk = blockIdx.x;
    const int k = blk >> 3;
    const int layer = k >> 4;
    const int grp = (blk & 7) * 16 + (k & 15);
    const int R = grp << 1;
    const int b = R >> 6, y0 = R & 63;

    const int tid = threadIdx.x;
    const int wid = tid >> 6, L = tid & 63;
    const int c = L & 15, q = L >> 4, q8 = q * 8;
    const int fh = wid & 1;
    const int f = fh * 16 + c;
    const int wr = wid >> 1;
    const int o  = wr - 4;

    const bf16x8* wpkv = (const bf16x8*)(layer ? wpk2 : wpk1);
    const float* bias = layer ? bias2 : bias1;
    float* cl = layer ? c2 : c1;
    float bv[4];
    #pragma unroll
    for (int g = 0; g < 4; ++g) bv[g] = bias[g * 32 + f];

    for (int j = 0; j <= 8; ++j) {
        const bool active = layer ? (j >= 1) : (j <= 7);
        if (active) {
            const int T0 = layer ? (2 * j - 2) : (2 * j);
            const float*  xA  = x + (size_t)(b * 16 + T0) * 131072;
            const float*  xB  = xA + 131072;
            const __bf16* h1A = h1buf + (size_t)(T0 & 3) * PLANE;
            const __bf16* h1B = h1buf + (size_t)((T0 + 1) & 3) * PLANE;
            const __bf16* hRA = layer ? (h2buf + (size_t)(((T0 - 1) >> 1) & 1) * PLANE)
                                      : (h1buf + (size_t)((T0 - 1) & 3) * PLANE);

            // ---- P1: stage tXA + tXB ----
            for (int i = tid; i < 2640; i += 1024) {
                const int tb = (i >= 1584);
                const int r2 = tb ? (i - 1584) : i;
                const int g = r2 & 3;
                const int rc = r2 >> 2;
                const int cc = rc % 66;
                const int row = rc / 66;
                const int yy = (tb ? y0 - 1 : y0 - 2) + row;
                const int xc = cc - 1;
                bf16x8 v = {};
                if ((unsigned)yy < 64u && (unsigned)xc < 64u) {
                    if (!layer) {
                        v = cvt8((tb ? xB : xA) + ((size_t)yy * 64 + xc) * 32 + g * 8);
                    } else {
                        const __bf16* s = tb ? h1B : h1A;
                        v = *(const bf16x8*)(s + (((size_t)(b * 64 + yy)) * 64 + xc) * 32 + g * 8);
                    }
                }
                *(bf16x8*)((tb ? tXB : tXA) + (row * 66 + cc) * 36 + g * 8) = v;
            }
            __syncthreads();

            // ---- P2: x-side compute || tRA staging + tHA zero ----
            f32x4 accU[4][4];
            if (wid < 8) {
                const int ra = y0 - 1 + wr;
                if ((unsigned)ra < 64u) {
                    #pragma unroll
                    for (int m = 0; m < 4; ++m)
                        #pragma unroll
                        for (int g = 0; g < 4; ++g)
                            accU[m][g] = (f32x4){bv[g], bv[g], bv[g], bv[g]};
                    #pragma unroll
                    for (int tap = 0; tap < 9; ++tap) {
                        const int dyk = tap / 3, dxk = tap - dyk * 3;
                        const int lb = ((wr + dyk) * 66 + c + dxk) * 36 + q8;
                        const bf16x8 a0 = *(const bf16x8*)(tXA + lb);
                        const bf16x8 a1 = *(const bf16x8*)(tXA + lb + 16 * 36);
                        const bf16x8 a2 = *(const bf16x8*)(tXA + lb + 32 * 36);
                        const bf16x8 a3 = *(const bf16x8*)(tXA + lb + 48 * 36);
                        const bf16x8* wp = wpkv + (size_t)((tap * 2) * 8 + fh * 4) * 64 + L;
                        MFMA16(a0, a1, a2, a3, wp, accU);
                    }
                }
            } else if (wid < 12) {
                #pragma unroll
                for (int m = 0; m < 4; ++m)
                    #pragma unroll
                    for (int g = 0; g < 4; ++g)
                        accU[m][g] = (f32x4){bv[g], bv[g], bv[g], bv[g]};
                #pragma unroll
                for (int tap = 0; tap < 9; ++tap) {
                    const int dyk = tap / 3, dxk = tap - dyk * 3;
                    const int lb = ((o + dyk) * 66 + c + dxk) * 36 + q8;
                    const bf16x8 a0 = *(const bf16x8*)(tXB + lb);
                    const bf16x8 a1 = *(const bf16x8*)(tXB + lb + 16 * 36);
                    const bf16x8 a2 = *(const bf16x8*)(tXB + lb + 32 * 36);
                    const bf16x8 a3 = *(const bf16x8*)(tXB + lb + 48 * 36);
                    const bf16x8* wp = wpkv + (size_t)((tap * 2) * 8 + fh * 4) * 64 + L;
                    MFMA16(a0, a1, a2, a3, wp, accU);
                }
            } else {
                const int t2 = tid - 768;
                if (T0 > 0) {
                    for (int i = t2; i < 1584; i += 256) {
                        const int g = i & 3;
                        const int rc = i >> 2;
                        const int cc = rc % 66;
                        const int row = rc / 66;
                        const int yy = y0 - 2 + row;
                        const int xc = cc - 1;
                        bf16x8 v = {};
                        if ((unsigned)yy < 64u && (unsigned)xc < 64u)
                            v = *(const bf16x8*)(hRA + (((size_t)(b * 64 + yy)) * 64 + xc) * 32 + g * 8);
                        *(bf16x8*)(tRA + (row * 66 + cc) * 36 + g * 8) = v;
                    }
                }
                for (int i = t2; i < 1188; i += 256)
                    *(bf16x8*)(tHA + i * 8) = (bf16x8){};
            }
            __syncthreads();

            // ---- P3: step-A h-side + epilogue A ----
            if (wid < 8) {
                const int ra = y0 - 1 + wr;
                const bool rv = ((unsigned)ra < 64u);
                if (rv) {
                    if (T0 > 0) {
                        #pragma unroll
                        for (int tap = 0; tap < 9; ++tap) {
                            const int dyk = tap / 3, dxk = tap - dyk * 3;
                            const int lb = ((wr + dyk) * 66 + c + dxk) * 36 + q8;
                            const bf16x8 h0 = *(const bf16x8*)(tRA + lb);
                            const bf16x8 h1v = *(const bf16x8*)(tRA + lb + 16 * 36);
                            const bf16x8 h2v = *(const bf16x8*)(tRA + lb + 32 * 36);
                            const bf16x8 h3v = *(const bf16x8*)(tRA + lb + 48 * 36);
                            const bf16x8* wp = wpkv + (size_t)((tap * 2 + 1) * 8 + fh * 4) * 64 + L;
                            MFMA16(h0, h1v, h2v, h3v, wp, accU);
                        }
                    }
                    const bool own = (wr == 1 || wr == 2);
                    const float* crd = cl + (size_t)((j - 1) & 1) * PLANE;
                    const size_t rowA = (size_t)(b * 64 + ra) * 2048;
                    #pragma unroll
                    for (int m = 0; m < 4; ++m) {
                        #pragma unroll
                        for (int r = 0; r < 4; ++r) {
                            const int px = m * 16 + q * 4 + r;
                            const float ig = fsigmoid(accU[m][0][r]);
                            const float fg = fsigmoid(accU[m][1][r]);
                            const float gg = ftanh(accU[m][2][r]);
                            const float og = fsigmoid(accU[m][3][r]);
                            const float cold = T0 ? crd[rowA + (size_t)px * 32 + f] : 0.0f;
                            const float cn = (T0 ? fg * cold : 0.0f) + ig * gg;
                            const float hv = og * ftanh(cn);
                            tHA[(wr * 66 + px + 1) * 36 + f] = (__bf16)hv;
                            if (own) {
                                cpass[(wr - 1) * 2048 + px * 32 + f] = cn;
                                if (layer)
                                    out[((size_t)(b * 16 + T0) * 4096 + (size_t)ra * 64 + px) * 32 + f] = hv;
                                else
                                    h1buf[(size_t)(T0 & 3) * PLANE + rowA + (size_t)px * 32 + f] = (__bf16)hv;
                            }
                        }
                    }
                }
            }
            __syncthreads();

            // ---- P4: step-B h-side + epilogue B ----
            if (wid >= 8 && wid < 12) {
                #pragma unroll
                for (int tap = 0; tap < 9; ++tap) {
                    const int dyk = tap / 3, dxk = tap - dyk * 3;
                    const int lb = ((o + dyk) * 66 + c + dxk) * 36 + q8;
                    const bf16x8 h0 = *(const bf16x8*)(tHA + lb);
                    const bf16x8 h1v = *(const bf16x8*)(tHA + lb + 16 * 36);
                    const bf16x8 h2v = *(const bf16x8*)(tHA + lb + 32 * 36);
                    const bf16x8 h3v = *(const bf16x8*)(tHA + lb + 48 * 36);
                    const bf16x8* wp = wpkv + (size_t)((tap * 2 + 1) * 8 + fh * 4) * 64 + L;
                    MFMA16(h0, h1v, h2v, h3v, wp, accU);
                }
                const int rb = y0 + o;
                float* cwr = cl + (size_t)(j & 1) * PLANE;
                __bf16* h2w = h2buf + (size_t)(((T0 + 1) >> 1) & 1) * PLANE;
                const size_t rowB = (size_t)(b * 64 + rb) * 2048;
                #pragma unroll
                for (int m = 0; m < 4; ++m) {
                    #pragma unroll
                    for (int r = 0; r < 4; ++r) {
                        const int px = m * 16 + q * 4 + r;
                        const float ig = fsigmoid(accU[m][0][r]);
                        const float fg = fsigmoid(accU[m][1][r]);
                        const float gg = ftanh(accU[m][2][r]);
                        const float og = fsigmoid(accU[m][3][r]);
                        const float cold = cpass[o * 2048 + px * 32 + f];
                        const float cn = fg * cold + ig * gg;
                        const float hv = og * ftanh(cn);
                        cwr[rowB + (size_t)px * 32 + f] = cn;
                        if (layer) {
                            out[((size_t)(b * 16 + T0 + 1) * 4096 + (size_t)rb * 64 + px) * 32 + f] = hv;
                            h2w[rowB + (size_t)px * 32 + f] = (__bf16)hv;
                        } else {
                            h1buf[(size_t)((T0 + 1) & 3) * PLANE + rowB + (size_t)px * 32 + f] = (__bf16)hv;
                        }
                    }
                }
            }
        }

        // ---- grid barrier (R5's proven recipe) ----
        if (j < 8) {
            __syncthreads();
            __threadfence();                 // release this block's writes
            __syncthreads();
            if (tid == 0) {
                int v = __hip_atomic_fetch_add(&cnt[j], 1, __ATOMIC_ACQ_REL,
                                               __HIP_MEMORY_SCOPE_AGENT);
                if (v == 255) {
                    __hip_atomic_store(gen, j + 1, __ATOMIC_RELEASE,
                                       __HIP_MEMORY_SCOPE_AGENT);
                } else {
                    int guard = 0;
                    while (__hip_atomic_load(gen, __ATOMIC_ACQUIRE,
                                             __HIP_MEMORY_SCOPE_AGENT) < j + 1) {
                        __builtin_amdgcn_s_sleep(2);
                        if (++guard > 2000000) break;   // bail, never hang
                    }
                }
            }
            __syncthreads();
            __threadfence();                 // acquire: drop stale cached lines
        }
    }
}

extern "C" void kernel_launch(void* const* d_in, const int* in_sizes, int n_in,
                              void* d_out, int out_size, void* d_ws, size_t ws_size,
                              hipStream_t stream)
{
    const float* x   = (const float*)d_in[0];
    const float* k1  = (const float*)d_in[1];
    const float* rk1 = (const float*)d_in[2];
    const float* b1  = (const float*)d_in[3];
    const float* k2  = (const float*)d_in[4];
    const float* rk2 = (const float*)d_in[5];
    const float* b2  = (const float*)d_in[6];
    float* out = (float*)d_out;

    int* cnt = (int*)d_ws;                          // 9 counters + gen
    int* gen = cnt + 16;
    __bf16* wpk1  = (__bf16*)((char*)d_ws + 256);
    __bf16* wpk2  = wpk1 + WPK_ELEMS;
    __bf16* h1buf = wpk2 + WPK_ELEMS;               // 4 planes bf16
    __bf16* h2buf = h1buf + 4 * (size_t)PLANE;      // 2 planes bf16
    float*  c1    = (float*)(h2buf + 2 * (size_t)PLANE);
    float*  c2    = c1 + 2 * (size_t)PLANE;

    hipMemsetAsync(d_ws, 0, 256, stream);
    pack_weights<<<(2 * WPK_ELEMS + 255) / 256, 256, 0, stream>>>(k1, rk1, k2, rk2, wpk1);

    void* args[] = {(void*)&x, (void*)&wpk1, (void*)&wpk2, (void*)&b1, (void*)&b2,
                    (void*)&h1buf, (void*)&h2buf, (void*)&c1, (void*)&c2,
                    (void*)&cnt, (void*)&gen, (void*)&out};
    hipLaunchCooperativeKernel((void*)clstm_coop18, dim3(256), dim3(1024), args, 0, stream);
}

// Round 19
// 230.404 us; speedup vs baseline: 10.2063x; 10.2063x over previous
//
#include <hip/hip_runtime.h>

// ConvLSTM2D x2, 2-step temporal blocking, 9 launches — best measured (230us).
// Launch j: L1 computes t=2j,2j+1; L2 computes t=2j-2,2j-1 (prev-launch deps).
// 256 blocks x 1024 thr.
//   P1: stage tXA + tXB (16 waves)
//   P2: waves 0-7 step-A x-side | waves 8-11 step-B x-side |
//       waves 12-15 stage tRA + zero tHA (hidden under compute)
//   P3: waves 0-7 step-A h-side + epilogue A (tHA/cpass/global)
//   P4: waves 8-11 step-B h-side + epilogue B
// ONE unified accU[4][4] per thread -> 64 accum regs under the 128-reg cap of
// 1024-thr blocks (4 waves/SIMD). No weight arrays (stream B-frags from L2:
// proven equal to LDS in R13 and avoids the R5/R7 spill).
// Persistent variants measured and rejected: R3 flag-spin (~60us/hop), R5 flat
// atomic barrier (+spill), R18 coop (fence-forced L2 flush, 1GB traffic).

typedef __bf16 bf16x8 __attribute__((ext_vector_type(8)));
typedef float f32x4 __attribute__((ext_vector_type(4)));

#define WPK_ELEMS 73728   // per layer: 18 kchunks * 8 ntiles * 64 lanes * 8
#define PLANE 524288      // 4*64*64*32 elems per plane

__device__ __forceinline__ float fsigmoid(float z) {
    return 1.0f / (1.0f + __expf(-z));
}
__device__ __forceinline__ float ftanh(float z) {
    z = fminf(15.0f, fmaxf(-15.0f, z));
    float e = __expf(2.0f * z);
    return (e - 1.0f) / (e + 1.0f);
}

__global__ __launch_bounds__(256) void pack_weights(
    const float* __restrict__ wk1, const float* __restrict__ wr1,
    const float* __restrict__ wk2, const float* __restrict__ wr2,
    __bf16* __restrict__ wpk)
{
    int i = blockIdx.x * 256 + threadIdx.x;
    if (i >= 2 * WPK_ELEMS) return;
    int layer = i / WPK_ELEMS;
    int r = i - layer * WPK_ELEMS;
    int j2 = r & 7;
    int L  = (r >> 3) & 63;
    int nt = (r >> 9) & 7;
    int cix = r >> 12;            // tap*2 + src
    int tap = cix >> 1, src = cix & 1;
    int s = ((L >> 4) << 3) + j2;
    int gate = nt & 3;
    int f = ((nt >> 2) << 4) + (L & 15);
    int n = (gate << 5) + f;
    const float* w = layer ? (src ? wr2 : wk2) : (src ? wr1 : wk1);
    wpk[i] = (__bf16)w[(tap * 32 + s) * 128 + n];
}

__device__ __forceinline__ bf16x8 cvt8(const float* p) {
    const float4 f0 = *(const float4*)p;
    const float4 f1 = *(const float4*)(p + 4);
    bf16x8 v;
    v[0] = (__bf16)f0.x; v[1] = (__bf16)f0.y;
    v[2] = (__bf16)f0.z; v[3] = (__bf16)f0.w;
    v[4] = (__bf16)f1.x; v[5] = (__bf16)f1.y;
    v[6] = (__bf16)f1.z; v[7] = (__bf16)f1.w;
    return v;
}

// 16 MFMAs: 4 A-tiles (M=64) x 4 gates, sharing one 4-fragment B load.
#define MFMA16(A0, A1, A2, A3, WP, ACC)                                                   \
    {                                                                                     \
        const bf16x8 w0 = WP[0], w1 = WP[64], w2 = WP[128], w3 = WP[192];                 \
        ACC[0][0] = __builtin_amdgcn_mfma_f32_16x16x32_bf16(A0, w0, ACC[0][0], 0, 0, 0);  \
        ACC[0][1] = __builtin_amdgcn_mfma_f32_16x16x32_bf16(A0, w1, ACC[0][1], 0, 0, 0);  \
        ACC[0][2] = __builtin_amdgcn_mfma_f32_16x16x32_bf16(A0, w2, ACC[0][2], 0, 0, 0);  \
        ACC[0][3] = __builtin_amdgcn_mfma_f32_16x16x32_bf16(A0, w3, ACC[0][3], 0, 0, 0);  \
        ACC[1][0] = __builtin_amdgcn_mfma_f32_16x16x32_bf16(A1, w0, ACC[1][0], 0, 0, 0);  \
        ACC[1][1] = __builtin_amdgcn_mfma_f32_16x16x32_bf16(A1, w1, ACC[1][1], 0, 0, 0);  \
        ACC[1][2] = __builtin_amdgcn_mfma_f32_16x16x32_bf16(A1, w2, ACC[1][2], 0, 0, 0);  \
        ACC[1][3] = __builtin_amdgcn_mfma_f32_16x16x32_bf16(A1, w3, ACC[1][3], 0, 0, 0);  \
        ACC[2][0] = __builtin_amdgcn_mfma_f32_16x16x32_bf16(A2, w0, ACC[2][0], 0, 0, 0);  \
        ACC[2][1] = __builtin_amdgcn_mfma_f32_16x16x32_bf16(A2, w1, ACC[2][1], 0, 0, 0);  \
        ACC[2][2] = __builtin_amdgcn_mfma_f32_16x16x32_bf16(A2, w2, ACC[2][2], 0, 0, 0);  \
        ACC[2][3] = __builtin_amdgcn_mfma_f32_16x16x32_bf16(A2, w3, ACC[2][3], 0, 0, 0);  \
        ACC[3][0] = __builtin_amdgcn_mfma_f32_16x16x32_bf16(A3, w0, ACC[3][0], 0, 0, 0);  \
        ACC[3][1] = __builtin_amdgcn_mfma_f32_16x16x32_bf16(A3, w1, ACC[3][1], 0, 0, 0);  \
        ACC[3][2] = __builtin_amdgcn_mfma_f32_16x16x32_bf16(A3, w2, ACC[3][2], 0, 0, 0);  \
        ACC[3][3] = __builtin_amdgcn_mfma_f32_16x16x32_bf16(A3, w3, ACC[3][3], 0, 0, 0);  \
    }

__global__ __launch_bounds__(1024, 1) void clstm_v17(
    const float* __restrict__ x,
    const __bf16* __restrict__ wpk1, const __bf16* __restrict__ wpk2,
    const float* __restrict__ bias1, const float* __restrict__ bias2,
    __bf16* __restrict__ h1buf,       // 4 planes, t%4
    __bf16* __restrict__ h2buf,       // 2 parity planes (odd t)
    float* __restrict__ c1,           // 2 parity planes (odd t)
    float* __restrict__ c2,
    float* __restrict__ out, int j)
{
    __shared__ __bf16 tXA[6 * 66 * 36];   // step-A input src rows y0-2..y0+3
    __shared__ __bf16 tRA[6 * 66 * 36];   // step-A recurrent src (h@T0-1)
    __shared__ __bf16 tXB[4 * 66 * 36];   // step-B input src rows y0-1..y0+2
    __shared__ __bf16 tHA[4 * 66 * 36];   // h@T0 rows y0-1..y0+2 (zero borders)
    __shared__ float  cpass[2 * 64 * 32]; // c@T0, own rows

    const int blk = blockIdx.x;
    const int k = blk >> 3;
    const int layer = k >> 4;
    if (layer ? (j < 1) : (j > 7)) return;
    const int grp = (blk & 7) * 16 + (k & 15);   // XCD-contiguous rows
    const int T0 = layer ? (2 * j - 2) : (2 * j);
    const int R = grp << 1;
    const int b = R >> 6, y0 = R & 63;

    const int tid = threadIdx.x;
    const int wid = tid >> 6, L = tid & 63;
    const int c = L & 15, q = L >> 4, q8 = q * 8;
    const int fh = wid & 1;               // valid for waves 0-11
    const int f = fh * 16 + c;
    const int wr = wid >> 1;              // waves 0-7: window row 0..3
    const int o  = wr - 4;                // waves 8-11: own row 0..1

    const bf16x8* wpkv = (const bf16x8*)(layer ? wpk2 : wpk1);
    const float* bias = layer ? bias2 : bias1;
    float* cl = layer ? c2 : c1;

    const float*  xA  = x + (size_t)(b * 16 + T0) * 131072;
    const float*  xB  = xA + 131072;
    const __bf16* h1A = h1buf + (size_t)(T0 & 3) * PLANE;
    const __bf16* h1B = h1buf + (size_t)((T0 + 1) & 3) * PLANE;
    const __bf16* hRA = layer ? (h2buf + (size_t)(((T0 - 1) >> 1) & 1) * PLANE)
                              : (h1buf + (size_t)((T0 - 1) & 3) * PLANE);

    // ================= P1: stage tXA + tXB ==================================
    for (int i = tid; i < 2640; i += 1024) {
        const int tb = (i >= 1584);
        const int r2 = tb ? (i - 1584) : i;
        const int g = r2 & 3;
        const int rc = r2 >> 2;
        const int cc = rc % 66;
        const int row = rc / 66;
        const int yy = (tb ? y0 - 1 : y0 - 2) + row;
        const int xc = cc - 1;
        bf16x8 v = {};
        if ((unsigned)yy < 64u && (unsigned)xc < 64u) {
            if (!layer) {
                v = cvt8((tb ? xB : xA) + ((size_t)yy * 64 + xc) * 32 + g * 8);
            } else {
                const __bf16* s = tb ? h1B : h1A;
                v = *(const bf16x8*)(s + (((size_t)(b * 64 + yy)) * 64 + xc) * 32 + g * 8);
            }
        }
        *(bf16x8*)((tb ? tXB : tXA) + (row * 66 + cc) * 36 + g * 8) = v;
    }
    __syncthreads();

    // ================= P2: x-side compute || tRA staging + tHA zero =========
    f32x4 accU[4][4];   // waves 0-7: step-A acc; waves 8-11: step-B acc

    if (wid < 8) {
        const int ra = y0 - 1 + wr;
        if ((unsigned)ra < 64u) {
            float bv[4];
            #pragma unroll
            for (int g = 0; g < 4; ++g) bv[g] = bias[g * 32 + f];
            #pragma unroll
            for (int m = 0; m < 4; ++m)
                #pragma unroll
                for (int g = 0; g < 4; ++g)
                    accU[m][g] = (f32x4){bv[g], bv[g], bv[g], bv[g]};

            #pragma unroll
            for (int tap = 0; tap < 9; ++tap) {
                const int dyk = tap / 3, dxk = tap - dyk * 3;
                const int lb = ((wr + dyk) * 66 + c + dxk) * 36 + q8;
                const bf16x8 a0 = *(const bf16x8*)(tXA + lb);
                const bf16x8 a1 = *(const bf16x8*)(tXA + lb + 16 * 36);
                const bf16x8 a2 = *(const bf16x8*)(tXA + lb + 32 * 36);
                const bf16x8 a3 = *(const bf16x8*)(tXA + lb + 48 * 36);
                const bf16x8* wp = wpkv + (size_t)((tap * 2) * 8 + fh * 4) * 64 + L;
                MFMA16(a0, a1, a2, a3, wp, accU);
            }
        }
    } else if (wid < 12) {
        float bv[4];
        #pragma unroll
        for (int g = 0; g < 4; ++g) bv[g] = bias[g * 32 + f];
        #pragma unroll
        for (int m = 0; m < 4; ++m)
            #pragma unroll
            for (int g = 0; g < 4; ++g)
                accU[m][g] = (f32x4){bv[g], bv[g], bv[g], bv[g]};

        #pragma unroll
        for (int tap = 0; tap < 9; ++tap) {
            const int dyk = tap / 3, dxk = tap - dyk * 3;
            const int lb = ((o + dyk) * 66 + c + dxk) * 36 + q8;
            const bf16x8 a0 = *(const bf16x8*)(tXB + lb);
            const bf16x8 a1 = *(const bf16x8*)(tXB + lb + 16 * 36);
            const bf16x8 a2 = *(const bf16x8*)(tXB + lb + 32 * 36);
            const bf16x8 a3 = *(const bf16x8*)(tXB + lb + 48 * 36);
            const bf16x8* wp = wpkv + (size_t)((tap * 2) * 8 + fh * 4) * 64 + L;
            MFMA16(a0, a1, a2, a3, wp, accU);
        }
    } else {
        const int t2 = tid - 768;             // 0..255
        if (T0 > 0) {
            for (int i = t2; i < 1584; i += 256) {
                const int g = i & 3;
                const int rc = i >> 2;
                const int cc = rc % 66;
                const int row = rc / 66;
                const int yy = y0 - 2 + row;
                const int xc = cc - 1;
                bf16x8 v = {};
                if ((unsigned)yy < 64u && (unsigned)xc < 64u)
                    v = *(const bf16x8*)(hRA + (((size_t)(b * 64 + yy)) * 64 + xc) * 32 + g * 8);
                *(bf16x8*)(tRA + (row * 66 + cc) * 36 + g * 8) = v;
            }
        }
        for (int i = t2; i < 1188; i += 256)
            *(bf16x8*)(tHA + i * 8) = (bf16x8){};
    }
    __syncthreads();

    // ================= P3: step-A h-side + epilogue A (waves 0-7) ===========
    if (wid < 8) {
        const int ra = y0 - 1 + wr;
        const bool rv = ((unsigned)ra < 64u);
        if (rv) {
            if (T0 > 0) {
                #pragma unroll
                for (int tap = 0; tap < 9; ++tap) {
                    const int dyk = tap / 3, dxk = tap - dyk * 3;
                    const int lb = ((wr + dyk) * 66 + c + dxk) * 36 + q8;
                    const bf16x8 h0 = *(const bf16x8*)(tRA + lb);
                    const bf16x8 h1v = *(const bf16x8*)(tRA + lb + 16 * 36);
                    const bf16x8 h2v = *(const bf16x8*)(tRA + lb + 32 * 36);
                    const bf16x8 h3v = *(const bf16x8*)(tRA + lb + 48 * 36);
                    const bf16x8* wp = wpkv + (size_t)((tap * 2 + 1) * 8 + fh * 4) * 64 + L;
                    MFMA16(h0, h1v, h2v, h3v, wp, accU);
                }
            }
            const bool own = (wr == 1 || wr == 2);
            const float* crd = cl + (size_t)((j - 1) & 1) * PLANE;
            const size_t rowA = (size_t)(b * 64 + ra) * 2048;
            #pragma unroll
            for (int m = 0; m < 4; ++m) {
                #pragma unroll
                for (int r = 0; r < 4; ++r) {
                    const int px = m * 16 + q * 4 + r;
                    const float ig = fsigmoid(accU[m][0][r]);
                    const float fg = fsigmoid(accU[m][1][r]);
                    const float gg = ftanh(accU[m][2][r]);
                    const float og = fsigmoid(accU[m][3][r]);
                    const float cold = T0 ? crd[rowA + (size_t)px * 32 + f] : 0.0f;
                    const float cn = (T0 ? fg * cold : 0.0f) + ig * gg;
                    const float hv = og * ftanh(cn);
                    tHA[(wr * 66 + px + 1) * 36 + f] = (__bf16)hv;
                    if (own) {
                        cpass[(wr - 1) * 2048 + px * 32 + f] = cn;
                        if (layer)
                            out[((size_t)(b * 16 + T0) * 4096 + (size_t)ra * 64 + px) * 32 + f] = hv;
                        else
                            h1buf[(size_t)(T0 & 3) * PLANE + rowA + (size_t)px * 32 + f] = (__bf16)hv;
                    }
                }
            }
        }
    }
    __syncthreads();

    // ================= P4: step-B h-side + epilogue B (waves 8-11) ==========
    if (wid >= 8 && wid < 12) {
        #pragma unroll
        for (int tap = 0; tap < 9; ++tap) {
            const int dyk = tap / 3, dxk = tap - dyk * 3;
            const int lb = ((o + dyk) * 66 + c + dxk) * 36 + q8;
            const bf16x8 h0 = *(const bf16x8*)(tHA + lb);
            const bf16x8 h1v = *(const bf16x8*)(tHA + lb + 16 * 36);
            const bf16x8 h2v = *(const bf16x8*)(tHA + lb + 32 * 36);
            const bf16x8 h3v = *(const bf16x8*)(tHA + lb + 48 * 36);
            const bf16x8* wp = wpkv + (size_t)((tap * 2 + 1) * 8 + fh * 4) * 64 + L;
            MFMA16(h0, h1v, h2v, h3v, wp, accU);
        }
        const int rb = y0 + o;
        float* cwr = cl + (size_t)(j & 1) * PLANE;
        __bf16* h2w = h2buf + (size_t)(((T0 + 1) >> 1) & 1) * PLANE;
        const size_t rowB = (size_t)(b * 64 + rb) * 2048;
        #pragma unroll
        for (int m = 0; m < 4; ++m) {
            #pragma unroll
            for (int r = 0; r < 4; ++r) {
                const int px = m * 16 + q * 4 + r;
                const float ig = fsigmoid(accU[m][0][r]);
                const float fg = fsigmoid(accU[m][1][r]);
                const float gg = ftanh(accU[m][2][r]);
                const float og = fsigmoid(accU[m][3][r]);
                const float cold = cpass[o * 2048 + px * 32 + f];
                const float cn = fg * cold + ig * gg;
                const float hv = og * ftanh(cn);
                cwr[rowB + (size_t)px * 32 + f] = cn;
                if (layer) {
                    out[((size_t)(b * 16 + T0 + 1) * 4096 + (size_t)rb * 64 + px) * 32 + f] = hv;
                    h2w[rowB + (size_t)px * 32 + f] = (__bf16)hv;
                } else {
                    h1buf[(size_t)((T0 + 1) & 3) * PLANE + rowB + (size_t)px * 32 + f] = (__bf16)hv;
                }
            }
        }
    }
}

extern "C" void kernel_launch(void* const* d_in, const int* in_sizes, int n_in,
                              void* d_out, int out_size, void* d_ws, size_t ws_size,
                              hipStream_t stream)
{
    const float* x   = (const float*)d_in[0];
    const float* k1  = (const float*)d_in[1];
    const float* rk1 = (const float*)d_in[2];
    const float* b1  = (const float*)d_in[3];
    const float* k2  = (const float*)d_in[4];
    const float* rk2 = (const float*)d_in[5];
    const float* b2  = (const float*)d_in[6];
    float* out = (float*)d_out;

    __bf16* wpk1  = (__bf16*)d_ws;
    __bf16* wpk2  = wpk1 + WPK_ELEMS;
    __bf16* h1buf = wpk2 + WPK_ELEMS;             // 4 planes bf16
    __bf16* h2buf = h1buf + 4 * (size_t)PLANE;    // 2 planes bf16
    float*  c1    = (float*)(h2buf + 2 * (size_t)PLANE);  // 2 planes fp32
    float*  c2    = c1 + 2 * (size_t)PLANE;

    pack_weights<<<(2 * WPK_ELEMS + 255) / 256, 256, 0, stream>>>(k1, rk1, k2, rk2, wpk1);

    for (int j = 0; j <= 8; ++j) {
        clstm_v17<<<256, 1024, 0, stream>>>(
            x, wpk1, wpk2, b1, b2, h1buf, h2buf, c1, c2, out, j);
    }
}